// Round 6
// baseline (258.053 us; speedup 1.0000x reference)
//
#include <hip/hip_runtime.h>
#include <cstdint>
#include <cstddef>

typedef unsigned short u16;
typedef unsigned char u8;
typedef __bf16 bf16x8 __attribute__((ext_vector_type(8)));
typedef float f32x4 __attribute__((ext_vector_type(4)));
typedef float f32x2 __attribute__((ext_vector_type(2)));
typedef u16 u16x4 __attribute__((ext_vector_type(4)));
typedef u16 u16x8 __attribute__((ext_vector_type(8)));

#define B_ 16384
#define D_ 64
#define MAXC_ 8
#define NCON_ 2000
#define NCONP_ 2048
#define TDIM_ 1024
#define HID_ 256

#define VMW(n) asm volatile("s_waitcnt vmcnt(" #n ")" ::: "memory")
#define BAR() __builtin_amdgcn_s_barrier()

__device__ inline u16 f2b(float f){
  unsigned u = __float_as_uint(f);
  u += 0x7fffu + ((u >> 16) & 1u);
  return (u16)(u >> 16);
}
__device__ inline float b2f(u16 u){ return __uint_as_float(((unsigned)u) << 16); }

__device__ inline unsigned pk2fp8(float a, float b){
  return (unsigned)__builtin_amdgcn_cvt_pk_fp8_f32(a, b, 0, false);
}
template<bool HI>
__device__ inline f32x2 unpk_fp8(unsigned v){
  return __builtin_amdgcn_cvt_pk_f32_fp8(v, HI);
}

__device__ inline void gload16(const void* g, void* l){
  __builtin_amdgcn_global_load_lds((const __attribute__((address_space(1))) unsigned*)g,
                                   (__attribute__((address_space(3))) unsigned*)l, 16, 0, 0);
}

__device__ inline float wsum(float v){
  #pragma unroll
  for (int o = 32; o; o >>= 1) v += __shfl_xor(v, o);
  return v;
}
__device__ inline float sigf(float x){ return 1.f / (1.f + __expf(-x)); }

// =================== k_prep ================================================
// [0,4096): q gather -> qb(bf16)+qn ; [4096,4608): concepts -> cb,cb8,cn ;
// [4608,6017): weights
__global__ __launch_bounds__(256) void k_prep(
    const float* __restrict__ ex, const int* __restrict__ pid,
    const float* __restrict__ con,
    const float* __restrict__ W1, const float* __restrict__ W2,
    const float* __restrict__ Wx, const float* __restrict__ Wh,
    const float* __restrict__ bx, const float* __restrict__ bh,
    u16* __restrict__ qb, float* __restrict__ qn,
    u16* __restrict__ cb, u8* __restrict__ cb8, float* __restrict__ cn,
    u16* __restrict__ W1T, u16* __restrict__ W2T, u16* __restrict__ WxhT,
    float* __restrict__ bxh)
{
  const int bid = blockIdx.x, tid = threadIdx.x;
  const int lane = tid & 63;
  if (bid < 4096){                                  // ---- q gather ----
    const int b = bid * 4 + (tid >> 6);
    const float* src = ex + (size_t)pid[b] * TDIM_;
    u16* dst = qb + (size_t)b * TDIM_;
    float ss = 0.f;
    #pragma unroll
    for (int c = 0; c < 4; ++c){
      float4 v = *(const float4*)(src + c * 256 + lane * 4);
      ss += v.x*v.x + v.y*v.y + v.z*v.z + v.w*v.w;
      u16x4 o = { f2b(v.x), f2b(v.y), f2b(v.z), f2b(v.w) };
      *(u16x4*)(dst + c * 256 + lane * 4) = o;
    }
    ss = wsum(ss);
    if (lane == 0) qn[b] = sqrtf(ss);
  } else if (bid < 4608){                           // ---- concepts ----
    const int r = (bid - 4096) * 4 + (tid >> 6);
    u16* dst = cb + (size_t)r * TDIM_;
    u8*  dst8 = cb8 + (size_t)r * TDIM_;
    if (r < NCON_){
      const float* src = con + (size_t)r * TDIM_;
      float ss = 0.f;
      #pragma unroll
      for (int c = 0; c < 4; ++c){
        float4 v = *(const float4*)(src + c * 256 + lane * 4);
        ss += v.x*v.x + v.y*v.y + v.z*v.z + v.w*v.w;
        u16x4 o = { f2b(v.x), f2b(v.y), f2b(v.z), f2b(v.w) };
        *(u16x4*)(dst + c * 256 + lane * 4) = o;
        unsigned lo = pk2fp8(v.x * 32.f, v.y * 32.f);
        unsigned hi = pk2fp8(v.z * 32.f, v.w * 32.f);
        *(unsigned*)(dst8 + c * 256 + lane * 4) = (lo & 0xffffu) | (hi << 16);
      }
      ss = wsum(ss);
      if (lane == 0) cn[r] = sqrtf(ss);
    } else {
      u16x4 z = { 0, 0, 0, 0 };
      #pragma unroll
      for (int c = 0; c < 4; ++c){
        *(u16x4*)(dst + c * 256 + lane * 4) = z;
        *(unsigned*)(dst8 + c * 256 + lane * 4) = 0u;
      }
    }
  } else {                                          // ---- weights ----
    int gid = (bid - 4608) * 256 + tid;
    if (gid < 262144){                       // W1T: n*1024 + k
      int n = gid >> 10, k = gid & 1023;
      W1T[gid] = f2b(W1[(size_t)k * 256 + n]);
    } else if (gid < 278528){                // W2T: n*256 + k
      int t = gid - 262144;
      int n = t >> 8, k = t & 255;
      W2T[t] = f2b(W2[(size_t)k * 64 + n]);
    } else if (gid < 360448){                // WxhT: c*320 + k, gate-interleaved
      int t = gid - 278528;
      int c = t / 320, k = t % 320;
      int g = (c >> 4) & 3;
      int d = (c >> 6) * 16 + (c & 15);
      float v = 0.f;
      if (k < 256){
        if (g == 0)      v = Wx[(size_t)k * 192 + d];
        else if (g == 1) v = Wx[(size_t)k * 192 + 64 + d];
        else if (g == 2) v = Wx[(size_t)k * 192 + 128 + d];
      } else {
        int kh = k - 256;
        if (g == 0)      v = Wh[(size_t)kh * 192 + d];
        else if (g == 1) v = Wh[(size_t)kh * 192 + 64 + d];
        else if (g == 3) v = Wh[(size_t)kh * 192 + 128 + d];
      }
      WxhT[t] = f2b(v);
    } else if (gid < 360704){                // bxh
      int c = gid - 360448;
      int g = (c >> 4) & 3;
      int d = (c >> 6) * 16 + (c & 15);
      float v;
      if (g == 0)      v = bx[d] + bh[d];
      else if (g == 1) v = bx[64 + d] + bh[64 + d];
      else if (g == 2) v = bx[128 + d];
      else             v = bh[128 + d];
      bxh[c] = v;
    }
  }
}

// =================== k_mlp: red = relu(A@W1+b1)@W2+b2 =======================
// 256 blocks x 512 thr. Every block: one 64-row q-tile. Blocks [0,128) also
// carry a 16-row c-tile (rows 16*bid) that SHARES the staged W1T tile.
__global__ __launch_bounds__(512, 4) void k_mlp(
    const u16* __restrict__ qb, const u16* __restrict__ cb,
    const u16* __restrict__ W1T, const float* __restrict__ b1,
    const u16* __restrict__ W2T, const float* __restrict__ b2,
    float* __restrict__ redq, float* __restrict__ redc)
{
  __shared__ char SM[76800];
  u16* As = (u16*)SM;                 // 8 KB  [64][64]
  u16* Ac = (u16*)(SM + 8192);        // 2 KB  [16][64]
  u16* Bs = (u16*)(SM + 10240);       // 32 KB [256][64]
  u16* Hs = (u16*)(SM + 43008);       // 32 KB [64][256]
  u16* Hc = (u16*)SM;                 // 8 KB  [16][256] (alias, post-loop)
  const int tid = threadIdx.x;
  const int lane = tid & 63;
  const int w = tid >> 6;
  const int lr = lane & 15, lq = lane >> 4;
  const int m0 = blockIdx.x << 6;
  const bool cblk = blockIdx.x < 128;
  const int c0 = blockIdx.x << 4;
  const int rf = w & 1, ch = w >> 1;

  const int arow = tid >> 3, asub = tid & 7;
  f32x4 acc[2][4] = {};
  f32x4 accc[2] = {};
  for (int kt = 0; kt < 16; ++kt){
    gload16(qb + (size_t)(m0 + arow) * 1024 + kt * 64 + ((asub ^ (arow & 7)) << 3),
            &As[tid * 8]);
    if (cblk && tid < 128)
      gload16(cb + (size_t)(c0 + arow) * 1024 + kt * 64 + ((asub ^ (arow & 7)) << 3),
              &Ac[tid * 8]);
    #pragma unroll
    for (int i = 0; i < 4; ++i){
      int cc = i * 512 + tid;
      int r2 = cc >> 3, s2 = cc & 7;
      gload16(W1T + (size_t)r2 * 1024 + kt * 64 + ((s2 ^ (r2 & 7)) << 3), &Bs[cc * 8]);
    }
    VMW(0);
    BAR();
    #pragma unroll
    for (int ks = 0; ks < 2; ++ks){
      const int kb = ks * 64 + lq * 16;
      bf16x8 af[2], bfr[4];
      #pragma unroll
      for (int fr = 0; fr < 2; ++fr){
        int rr = rf * 32 + fr * 16 + lr;
        af[fr] = *(const bf16x8*)((const char*)As + rr * 128 + (kb ^ ((rr & 7) << 4)));
      }
      #pragma unroll
      for (int fc = 0; fc < 4; ++fc){
        int rr = ch * 64 + fc * 16 + lr;
        bfr[fc] = *(const bf16x8*)((const char*)Bs + rr * 128 + (kb ^ ((rr & 7) << 4)));
      }
      #pragma unroll
      for (int fr = 0; fr < 2; ++fr)
        #pragma unroll
        for (int fc = 0; fc < 4; ++fc)
          acc[fr][fc] = __builtin_amdgcn_mfma_f32_16x16x32_bf16(af[fr], bfr[fc],
                                                                acc[fr][fc], 0, 0, 0);
      if (cblk){
        bf16x8 afc = *(const bf16x8*)((const char*)Ac + lr * 128 + (kb ^ ((lr & 7) << 4)));
        #pragma unroll
        for (int t = 0; t < 2; ++t)
          accc[t] = __builtin_amdgcn_mfma_f32_16x16x32_bf16(afc, bfr[rf * 2 + t],
                                                            accc[t], 0, 0, 0);
      }
    }
    BAR();
  }
  // hidden -> LDS (bias + relu + bf16), swizzled
  #pragma unroll
  for (int fr = 0; fr < 2; ++fr)
    #pragma unroll
    for (int fc = 0; fc < 4; ++fc){
      int col = ch * 64 + fc * 16 + lr;
      float bv = b1[col];
      #pragma unroll
      for (int j = 0; j < 4; ++j){
        int rr = rf * 32 + fr * 16 + lq * 4 + j;
        float v = fmaxf(acc[fr][fc][j] + bv, 0.f);
        *(u16*)((char*)Hs + rr * 512 + ((col * 2) ^ ((rr & 7) << 4))) = f2b(v);
      }
    }
  if (cblk){
    #pragma unroll
    for (int t = 0; t < 2; ++t){
      int col = w * 32 + t * 16 + lr;
      float bv = b1[col];
      #pragma unroll
      for (int j = 0; j < 4; ++j){
        int rr = lq * 4 + j;
        float v = fmaxf(accc[t][j] + bv, 0.f);
        *(u16*)((char*)Hc + rr * 512 + ((col * 2) ^ ((rr & 7) << 4))) = f2b(v);
      }
    }
  }
  __syncthreads();
  // layer 2 (q): [64,256] @ W2T[64,256]^T
  const int rf2 = w & 3, cp = w >> 2;
  bf16x8 w2f[8][2];
  #pragma unroll
  for (int ks2 = 0; ks2 < 8; ++ks2)
    #pragma unroll
    for (int t = 0; t < 2; ++t){
      int row64 = (cp * 2 + t) * 16 + lr;
      w2f[ks2][t] = *(const bf16x8*)(W2T + (size_t)row64 * 256 + ks2 * 32 + lq * 8);
    }
  f32x4 acc2[2] = {};
  #pragma unroll
  for (int ks2 = 0; ks2 < 8; ++ks2){
    int rr = rf2 * 16 + lr;
    int kb2 = ks2 * 64 + lq * 16;
    bf16x8 af2 = *(const bf16x8*)((const char*)Hs + rr * 512 + (kb2 ^ ((rr & 7) << 4)));
    #pragma unroll
    for (int t = 0; t < 2; ++t)
      acc2[t] = __builtin_amdgcn_mfma_f32_16x16x32_bf16(af2, w2f[ks2][t], acc2[t], 0, 0, 0);
  }
  #pragma unroll
  for (int t = 0; t < 2; ++t){
    int col = (cp * 2 + t) * 16 + lr;
    float bv = b2[col];
    #pragma unroll
    for (int j = 0; j < 4; ++j){
      int rr = m0 + rf2 * 16 + lq * 4 + j;
      redq[(size_t)rr * 64 + col] = acc2[t][j] + bv;
    }
  }
  // layer 2 (c): [16,256] -> [16,64], waves 0-3
  if (cblk && w < 4){
    bf16x8 w2fc[8];
    #pragma unroll
    for (int ks2 = 0; ks2 < 8; ++ks2){
      int row64 = w * 16 + lr;
      w2fc[ks2] = *(const bf16x8*)(W2T + (size_t)row64 * 256 + ks2 * 32 + lq * 8);
    }
    f32x4 acc2c = {};
    #pragma unroll
    for (int ks2 = 0; ks2 < 8; ++ks2){
      int kb2 = ks2 * 64 + lq * 16;
      bf16x8 af2 = *(const bf16x8*)((const char*)Hc + lr * 512 + (kb2 ^ ((lr & 7) << 4)));
      acc2c = __builtin_amdgcn_mfma_f32_16x16x32_bf16(af2, w2fc[ks2], acc2c, 0, 0, 0);
    }
    int col = w * 16 + lr;
    float bv = b2[col];
    #pragma unroll
    for (int j = 0; j < 4; ++j){
      int rr = c0 + lq * 4 + j;
      redc[(size_t)rr * 64 + col] = acc2c[j] + bv;
    }
  }
}

// =================== k_mixgru: mix + GRU, 512 blocks x 32 rows ==============
__global__ __launch_bounds__(512, 4) void k_mixgru(
    const u16* __restrict__ qb, const u8* __restrict__ cb8,
    const float* __restrict__ qn, const float* __restrict__ cn,
    const int* __restrict__ rci, const int* __restrict__ filt,
    const float* __restrict__ redq, const float* __restrict__ redc,
    const float* __restrict__ h, const float* __restrict__ emb,
    const float* __restrict__ op, const float* __restrict__ Wp,
    const float* __restrict__ bp, const u16* __restrict__ WxhT,
    const float* __restrict__ bxh, float* __restrict__ prob_out,
    float* __restrict__ outh)
{
  __shared__ u16 XH[32 * 320];     // 20 KB, row stride 640 B, XOR-swizzled
  __shared__ u16 Bs[256 * 64];     // 32 KB
  const int tid = threadIdx.x;
  const int lane = tid & 63;
  const int w = tid >> 6;
  const int m0 = blockIdx.x << 5;

  auto stageB = [&](int kt){
    #pragma unroll
    for (int i = 0; i < 4; ++i){
      int cc = i * 512 + tid;
      int r2 = cc >> 3, s2 = cc & 7;
      gload16(WxhT + (size_t)r2 * 320 + kt * 64 + ((s2 ^ (r2 & 7)) << 3), &Bs[cc * 8]);
    }
  };
  stageB(0);   // flies under the mix phase

  // ---------------- mix phase: 4 rows per wave ----------------
  for (int i = 0; i < 4; ++i){
    const int r = w * 4 + i;
    const int b = m0 + r;
    const u16* qrow = qb + (size_t)b * TDIM_ + lane * 16;
    u16x8 qa = *(const u16x8*)qrow;
    u16x8 qc = *(const u16x8*)(qrow + 8);
    float qf[16];
    #pragma unroll
    for (int k = 0; k < 8; ++k){ qf[k] = b2f(qa[k]); qf[8 + k] = b2f(qc[k]); }
    int idxm[MAXC_];
    #pragma unroll
    for (int m = 0; m < MAXC_; ++m) idxm[m] = rci[b * MAXC_ + m];
    float dots[MAXC_];
    #pragma unroll
    for (int m = 0; m < MAXC_; ++m){
      uint4 cw = *(const uint4*)(cb8 + (size_t)idxm[m] * TDIM_ + lane * 16);
      float s = 0.f; f32x2 p;
      p = unpk_fp8<false>(cw.x); s += qf[0]*p[0]  + qf[1]*p[1];
      p = unpk_fp8<true >(cw.x); s += qf[2]*p[0]  + qf[3]*p[1];
      p = unpk_fp8<false>(cw.y); s += qf[4]*p[0]  + qf[5]*p[1];
      p = unpk_fp8<true >(cw.y); s += qf[6]*p[0]  + qf[7]*p[1];
      p = unpk_fp8<false>(cw.z); s += qf[8]*p[0]  + qf[9]*p[1];
      p = unpk_fp8<true >(cw.z); s += qf[10]*p[0] + qf[11]*p[1];
      p = unpk_fp8<false>(cw.w); s += qf[12]*p[0] + qf[13]*p[1];
      p = unpk_fp8<true >(cw.w); s += qf[14]*p[0] + qf[15]*p[1];
      dots[m] = s;
    }
    #pragma unroll
    for (int o = 32; o; o >>= 1){
      #pragma unroll
      for (int m = 0; m < MAXC_; ++m) dots[m] += __shfl_xor(dots[m], o);
    }
    const float qnb = qn[b];
    float sv[MAXC_]; float mx = -3.0e38f;
    #pragma unroll
    for (int m = 0; m < MAXC_; ++m){
      float dnm = fmaxf(qnb * cn[idxm[m]], 1e-8f);
      float s = (filt[b * MAXC_ + m] == 0) ? -1e9f : dots[m] * (1.f / 32.f) / dnm;
      sv[m] = s; mx = fmaxf(mx, s);
    }
    float se = 0.f;
    #pragma unroll
    for (int m = 0; m < MAXC_; ++m){ sv[m] = __expf(sv[m] - mx); se += sv[m]; }
    const float inv = 1.f / se;
    float rep = 0.f;
    #pragma unroll
    for (int m = 0; m < MAXC_; ++m) rep += sv[m] * redc[(size_t)idxm[m] * D_ + lane];
    rep *= inv;
    const float v0 = redq[(size_t)b * D_ + lane];
    const float hv = h[(size_t)b * D_ + lane];
    const float e0 = emb[(size_t)b * 128 + lane];
    const float e1 = emb[(size_t)b * 128 + 64 + lane];
    float p = hv * Wp[lane] + v0 * Wp[64 + lane] + rep * Wp[128 + lane]
            + e0 * Wp[192 + lane] + e1 * Wp[256 + lane];
    p = wsum(p);
    if (lane == 0) prob_out[b] = p + bp[0];
    const float o = op[b], om = 1.f - o;
    auto xst = [&](int col, float v){
      *(u16*)((char*)XH + r * 640 + ((col * 2) ^ ((r & 7) << 4))) = f2b(v);
    };
    xst(lane,        v0 * o  + e0 * om);
    xst(64 + lane,   rep * o + e1 * om);
    xst(128 + lane,  v0 * om + e0 * o);
    xst(192 + lane,  rep * om + e1 * o);
    xst(256 + lane,  hv);
  }
  __syncthreads();

  // ---------------- GRU GEMM: [32,320]@[320,256], wave tile 16x64 ----------
  const int lr = lane & 15, lq = lane >> 4;
  const int rh = w & 1, cc = w >> 1;
  f32x4 acc[4] = {};
  for (int kt = 0; kt < 5; ++kt){
    VMW(0);
    BAR();
    #pragma unroll
    for (int ks = 0; ks < 2; ++ks){
      const int kb = ks * 64 + lq * 16;
      int rra = rh * 16 + lr;
      bf16x8 af = *(const bf16x8*)((const char*)XH + rra * 640 +
                                   ((kt * 128 + kb) ^ ((rra & 7) << 4)));
      bf16x8 bfr[4];
      #pragma unroll
      for (int fc = 0; fc < 4; ++fc){
        int rr = cc * 64 + fc * 16 + lr;
        bfr[fc] = *(const bf16x8*)((const char*)Bs + rr * 128 + (kb ^ ((rr & 7) << 4)));
      }
      #pragma unroll
      for (int fc = 0; fc < 4; ++fc)
        acc[fc] = __builtin_amdgcn_mfma_f32_16x16x32_bf16(af, bfr[fc], acc[fc], 0, 0, 0);
    }
    BAR();
    if (kt < 4) stageB(kt + 1);
  }
  const int d = cc * 16 + lr;
  float bg[4];
  #pragma unroll
  for (int g = 0; g < 4; ++g) bg[g] = bxh[cc * 64 + g * 16 + lr];
  #pragma unroll
  for (int j = 0; j < 4; ++j){
    float rv = sigf(acc[0][j] + bg[0]);
    float zv = sigf(acc[1][j] + bg[1]);
    float nv = tanhf(acc[2][j] + bg[2] + rv * (acc[3][j] + bg[3]));
    int rr = m0 + rh * 16 + lq * 4 + j;
    float hv = h[(size_t)rr * 64 + d];
    outh[(size_t)rr * 64 + d] = (1.f - zv) * nv + zv * hv;
  }
}

extern "C" void kernel_launch(void* const* d_in, const int* in_sizes, int n_in,
                              void* d_out, int out_size, void* d_ws, size_t ws_size,
                              hipStream_t stream) {
  const int*   prob_ids = (const int*)  d_in[0];
  const int*   rci      = (const int*)  d_in[1];
  const int*   filt     = (const int*)  d_in[2];
  const float* h        = (const float*)d_in[3];
  const float* emb      = (const float*)d_in[4];
  const float* op       = (const float*)d_in[5];
  const float* ex       = (const float*)d_in[6];
  const float* con      = (const float*)d_in[7];
  const float* W1       = (const float*)d_in[8];
  const float* b1       = (const float*)d_in[9];
  const float* W2       = (const float*)d_in[10];
  const float* b2       = (const float*)d_in[11];
  const float* Wp       = (const float*)d_in[12];
  const float* bp       = (const float*)d_in[13];
  const float* Wx       = (const float*)d_in[14];
  const float* Wh       = (const float*)d_in[15];
  const float* bx       = (const float*)d_in[16];
  const float* bh       = (const float*)d_in[17];
  float* out = (float*)d_out;

  char* w = (char*)d_ws;
  size_t off = 0;
  auto alloc = [&](size_t bytes){ size_t o = off; off = (off + bytes + 255) & ~(size_t)255; return o; };
  u16*   qb   = (u16*)  (w + alloc((size_t)B_ * TDIM_ * 2));      // 32 MB
  u16*   cb   = (u16*)  (w + alloc((size_t)NCONP_ * TDIM_ * 2));  // 4 MB
  u8*    cb8  = (u8*)   (w + alloc((size_t)NCONP_ * TDIM_));      // 2 MB
  float* qn   = (float*)(w + alloc((size_t)B_ * 4));
  float* cn   = (float*)(w + alloc((size_t)NCONP_ * 4));
  float* redq = (float*)(w + alloc((size_t)B_ * D_ * 4));         // 4 MB
  float* redc = (float*)(w + alloc((size_t)NCONP_ * D_ * 4));
  u16*   W1T  = (u16*)  (w + alloc((size_t)HID_ * TDIM_ * 2));
  u16*   W2T  = (u16*)  (w + alloc((size_t)D_ * HID_ * 2));
  u16*   WxhT = (u16*)  (w + alloc((size_t)256 * 320 * 2));
  float* bxh  = (float*)(w + alloc((size_t)256 * 4));

  k_prep<<<6017, 256, 0, stream>>>(ex, prob_ids, con, W1, W2, Wx, Wh, bx, bh,
                                   qb, qn, cb, cb8, cn, W1T, W2T, WxhT, bxh);
  k_mlp<<<256, 512, 0, stream>>>(qb, cb, W1T, b1, W2T, b2, redq, redc);
  k_mixgru<<<512, 512, 0, stream>>>(qb, cb8, qn, cn, rci, filt, redq, redc,
                                    h, emb, op, Wp, bp, WxhT, bxh, out, out + B_);
}

// Round 7
// 129.624 us; speedup vs baseline: 1.9908x; 1.9908x over previous
//
#include <hip/hip_runtime.h>
#include <cstdint>
#include <cstddef>

typedef unsigned short u16;
typedef unsigned char u8;
typedef __bf16 bf16x8 __attribute__((ext_vector_type(8)));
typedef float f32x4 __attribute__((ext_vector_type(4)));
typedef float f32x2 __attribute__((ext_vector_type(2)));
typedef u16 u16x4 __attribute__((ext_vector_type(4)));
typedef u16 u16x8 __attribute__((ext_vector_type(8)));

#define B_ 16384
#define D_ 64
#define MAXC_ 8
#define NCON_ 2000
#define NCONP_ 2048
#define TDIM_ 1024
#define HID_ 256

#define VMW(n) asm volatile("s_waitcnt vmcnt(" #n ")" ::: "memory")
#define BAR() __builtin_amdgcn_s_barrier()

__device__ inline u16 f2b(float f){
  unsigned u = __float_as_uint(f);
  u += 0x7fffu + ((u >> 16) & 1u);
  return (u16)(u >> 16);
}
__device__ inline float b2f(u16 u){ return __uint_as_float(((unsigned)u) << 16); }

__device__ inline unsigned pk2fp8(float a, float b){
  return (unsigned)__builtin_amdgcn_cvt_pk_fp8_f32(a, b, 0, false);
}
template<bool HI>
__device__ inline f32x2 unpk_fp8(unsigned v){
  return __builtin_amdgcn_cvt_pk_f32_fp8(v, HI);
}

__device__ inline void gload16(const void* g, void* l){
  __builtin_amdgcn_global_load_lds((const __attribute__((address_space(1))) unsigned*)g,
                                   (__attribute__((address_space(3))) unsigned*)l, 16, 0, 0);
}

__device__ inline float wsum(float v){
  #pragma unroll
  for (int o = 32; o; o >>= 1) v += __shfl_xor(v, o);
  return v;
}
__device__ inline float sigf(float x){ return 1.f / (1.f + __expf(-x)); }

// =================== k_prep ================================================
// [0,4096): q gather -> qb(bf16)+qn ; [4096,4608): concepts -> cb,cb8,cn ;
// [4608,6017): weights
__global__ __launch_bounds__(256) void k_prep(
    const float* __restrict__ ex, const int* __restrict__ pid,
    const float* __restrict__ con,
    const float* __restrict__ W1, const float* __restrict__ W2,
    const float* __restrict__ Wx, const float* __restrict__ Wh,
    const float* __restrict__ bx, const float* __restrict__ bh,
    u16* __restrict__ qb, float* __restrict__ qn,
    u16* __restrict__ cb, u8* __restrict__ cb8, float* __restrict__ cn,
    u16* __restrict__ W1T, u16* __restrict__ W2T, u16* __restrict__ WxhT,
    float* __restrict__ bxh)
{
  const int bid = blockIdx.x, tid = threadIdx.x;
  const int lane = tid & 63;
  if (bid < 4096){                                  // ---- q gather ----
    const int b = bid * 4 + (tid >> 6);
    const float* src = ex + (size_t)pid[b] * TDIM_;
    u16* dst = qb + (size_t)b * TDIM_;
    float ss = 0.f;
    #pragma unroll
    for (int c = 0; c < 4; ++c){
      float4 v = *(const float4*)(src + c * 256 + lane * 4);
      ss += v.x*v.x + v.y*v.y + v.z*v.z + v.w*v.w;
      u16x4 o = { f2b(v.x), f2b(v.y), f2b(v.z), f2b(v.w) };
      *(u16x4*)(dst + c * 256 + lane * 4) = o;
    }
    ss = wsum(ss);
    if (lane == 0) qn[b] = sqrtf(ss);
  } else if (bid < 4608){                           // ---- concepts ----
    const int r = (bid - 4096) * 4 + (tid >> 6);
    u16* dst = cb + (size_t)r * TDIM_;
    u8*  dst8 = cb8 + (size_t)r * TDIM_;
    if (r < NCON_){
      const float* src = con + (size_t)r * TDIM_;
      float ss = 0.f;
      #pragma unroll
      for (int c = 0; c < 4; ++c){
        float4 v = *(const float4*)(src + c * 256 + lane * 4);
        ss += v.x*v.x + v.y*v.y + v.z*v.z + v.w*v.w;
        u16x4 o = { f2b(v.x), f2b(v.y), f2b(v.z), f2b(v.w) };
        *(u16x4*)(dst + c * 256 + lane * 4) = o;
        unsigned lo = pk2fp8(v.x * 32.f, v.y * 32.f);
        unsigned hi = pk2fp8(v.z * 32.f, v.w * 32.f);
        *(unsigned*)(dst8 + c * 256 + lane * 4) = (lo & 0xffffu) | (hi << 16);
      }
      ss = wsum(ss);
      if (lane == 0) cn[r] = sqrtf(ss);
    } else {
      u16x4 z = { 0, 0, 0, 0 };
      #pragma unroll
      for (int c = 0; c < 4; ++c){
        *(u16x4*)(dst + c * 256 + lane * 4) = z;
        *(unsigned*)(dst8 + c * 256 + lane * 4) = 0u;
      }
    }
  } else {                                          // ---- weights ----
    int gid = (bid - 4608) * 256 + tid;
    if (gid < 262144){                       // W1T: n*1024 + k
      int n = gid >> 10, k = gid & 1023;
      W1T[gid] = f2b(W1[(size_t)k * 256 + n]);
    } else if (gid < 278528){                // W2T: n*256 + k
      int t = gid - 262144;
      int n = t >> 8, k = t & 255;
      W2T[t] = f2b(W2[(size_t)k * 64 + n]);
    } else if (gid < 360448){                // WxhT: c*320 + k, gate-interleaved
      int t = gid - 278528;
      int c = t / 320, k = t % 320;
      int g = (c >> 4) & 3;
      int d = (c >> 6) * 16 + (c & 15);
      float v = 0.f;
      if (k < 256){
        if (g == 0)      v = Wx[(size_t)k * 192 + d];
        else if (g == 1) v = Wx[(size_t)k * 192 + 64 + d];
        else if (g == 2) v = Wx[(size_t)k * 192 + 128 + d];
      } else {
        int kh = k - 256;
        if (g == 0)      v = Wh[(size_t)kh * 192 + d];
        else if (g == 1) v = Wh[(size_t)kh * 192 + 64 + d];
        else if (g == 3) v = Wh[(size_t)kh * 192 + 128 + d];
      }
      WxhT[t] = f2b(v);
    } else if (gid < 360704){                // bxh
      int c = gid - 360448;
      int g = (c >> 4) & 3;
      int d = (c >> 6) * 16 + (c & 15);
      float v;
      if (g == 0)      v = bx[d] + bh[d];
      else if (g == 1) v = bx[64 + d] + bh[64 + d];
      else if (g == 2) v = bx[128 + d];
      else             v = bh[128 + d];
      bxh[c] = v;
    }
  }
}

// =================== k_mlp: red = relu(A@W1+b1)@W2+b2 =======================
// 256 blocks x 512 thr. Every block: one 64-row q-tile. Blocks [0,128) also
// carry a 16-row c-tile (rows 16*bid) that SHARES the staged W1T tile.
__global__ __launch_bounds__(512, 4) void k_mlp(
    const u16* __restrict__ qb, const u16* __restrict__ cb,
    const u16* __restrict__ W1T, const float* __restrict__ b1,
    const u16* __restrict__ W2T, const float* __restrict__ b2,
    float* __restrict__ redq, float* __restrict__ redc)
{
  __shared__ char SM[76800];
  u16* As = (u16*)SM;                 // 8 KB  [64][64]
  u16* Ac = (u16*)(SM + 8192);        // 2 KB  [16][64]
  u16* Bs = (u16*)(SM + 10240);       // 32 KB [256][64]
  u16* Hs = (u16*)(SM + 43008);       // 32 KB [64][256]
  u16* Hc = (u16*)SM;                 // 8 KB  [16][256] (alias, post-loop)
  const int tid = threadIdx.x;
  const int lane = tid & 63;
  const int w = tid >> 6;
  const int lr = lane & 15, lq = lane >> 4;
  const int m0 = blockIdx.x << 6;
  const bool cblk = blockIdx.x < 128;
  const int c0 = blockIdx.x << 4;
  const int rf = w & 1, ch = w >> 1;

  const int arow = tid >> 3, asub = tid & 7;
  f32x4 acc[2][4] = {};
  f32x4 accc[2] = {};
  for (int kt = 0; kt < 16; ++kt){
    gload16(qb + (size_t)(m0 + arow) * 1024 + kt * 64 + ((asub ^ (arow & 7)) << 3),
            &As[tid * 8]);
    if (cblk && tid < 128)
      gload16(cb + (size_t)(c0 + arow) * 1024 + kt * 64 + ((asub ^ (arow & 7)) << 3),
              &Ac[tid * 8]);
    #pragma unroll
    for (int i = 0; i < 4; ++i){
      int cc = i * 512 + tid;
      int r2 = cc >> 3, s2 = cc & 7;
      gload16(W1T + (size_t)r2 * 1024 + kt * 64 + ((s2 ^ (r2 & 7)) << 3), &Bs[cc * 8]);
    }
    VMW(0);
    BAR();
    #pragma unroll
    for (int ks = 0; ks < 2; ++ks){
      const int kb = ks * 64 + lq * 16;
      bf16x8 af[2], bfr[4];
      #pragma unroll
      for (int fr = 0; fr < 2; ++fr){
        int rr = rf * 32 + fr * 16 + lr;
        af[fr] = *(const bf16x8*)((const char*)As + rr * 128 + (kb ^ ((rr & 7) << 4)));
      }
      #pragma unroll
      for (int fc = 0; fc < 4; ++fc){
        int rr = ch * 64 + fc * 16 + lr;
        bfr[fc] = *(const bf16x8*)((const char*)Bs + rr * 128 + (kb ^ ((rr & 7) << 4)));
      }
      #pragma unroll
      for (int fr = 0; fr < 2; ++fr)
        #pragma unroll
        for (int fc = 0; fc < 4; ++fc)
          acc[fr][fc] = __builtin_amdgcn_mfma_f32_16x16x32_bf16(af[fr], bfr[fc],
                                                                acc[fr][fc], 0, 0, 0);
      if (cblk){
        bf16x8 afc = *(const bf16x8*)((const char*)Ac + lr * 128 + (kb ^ ((lr & 7) << 4)));
        // rule #20: NO runtime index into bfr[] — wave-uniform branch on rf
        bf16x8 cb0, cb1;
        if (rf == 0){ cb0 = bfr[0]; cb1 = bfr[1]; }
        else        { cb0 = bfr[2]; cb1 = bfr[3]; }
        accc[0] = __builtin_amdgcn_mfma_f32_16x16x32_bf16(afc, cb0, accc[0], 0, 0, 0);
        accc[1] = __builtin_amdgcn_mfma_f32_16x16x32_bf16(afc, cb1, accc[1], 0, 0, 0);
      }
    }
    BAR();
  }
  // hidden -> LDS (bias + relu + bf16), swizzled
  #pragma unroll
  for (int fr = 0; fr < 2; ++fr)
    #pragma unroll
    for (int fc = 0; fc < 4; ++fc){
      int col = ch * 64 + fc * 16 + lr;
      float bv = b1[col];
      #pragma unroll
      for (int j = 0; j < 4; ++j){
        int rr = rf * 32 + fr * 16 + lq * 4 + j;
        float v = fmaxf(acc[fr][fc][j] + bv, 0.f);
        *(u16*)((char*)Hs + rr * 512 + ((col * 2) ^ ((rr & 7) << 4))) = f2b(v);
      }
    }
  if (cblk){
    #pragma unroll
    for (int t = 0; t < 2; ++t){
      int col = w * 32 + t * 16 + lr;
      float bv = b1[col];
      #pragma unroll
      for (int j = 0; j < 4; ++j){
        int rr = lq * 4 + j;
        float v = fmaxf(accc[t][j] + bv, 0.f);
        *(u16*)((char*)Hc + rr * 512 + ((col * 2) ^ ((rr & 7) << 4))) = f2b(v);
      }
    }
  }
  __syncthreads();
  // layer 2 (q): [64,256] @ W2T[64,256]^T
  const int rf2 = w & 3, cp = w >> 2;
  bf16x8 w2f[8][2];
  #pragma unroll
  for (int ks2 = 0; ks2 < 8; ++ks2)
    #pragma unroll
    for (int t = 0; t < 2; ++t){
      int row64 = (cp * 2 + t) * 16 + lr;
      w2f[ks2][t] = *(const bf16x8*)(W2T + (size_t)row64 * 256 + ks2 * 32 + lq * 8);
    }
  f32x4 acc2[2] = {};
  #pragma unroll
  for (int ks2 = 0; ks2 < 8; ++ks2){
    int rr = rf2 * 16 + lr;
    int kb2 = ks2 * 64 + lq * 16;
    bf16x8 af2 = *(const bf16x8*)((const char*)Hs + rr * 512 + (kb2 ^ ((rr & 7) << 4)));
    #pragma unroll
    for (int t = 0; t < 2; ++t)
      acc2[t] = __builtin_amdgcn_mfma_f32_16x16x32_bf16(af2, w2f[ks2][t], acc2[t], 0, 0, 0);
  }
  #pragma unroll
  for (int t = 0; t < 2; ++t){
    int col = (cp * 2 + t) * 16 + lr;
    float bv = b2[col];
    #pragma unroll
    for (int j = 0; j < 4; ++j){
      int rr = m0 + rf2 * 16 + lq * 4 + j;
      redq[(size_t)rr * 64 + col] = acc2[t][j] + bv;
    }
  }
  // layer 2 (c): [16,256] -> [16,64], waves 0-3
  if (cblk && w < 4){
    bf16x8 w2fc[8];
    #pragma unroll
    for (int ks2 = 0; ks2 < 8; ++ks2){
      int row64 = w * 16 + lr;
      w2fc[ks2] = *(const bf16x8*)(W2T + (size_t)row64 * 256 + ks2 * 32 + lq * 8);
    }
    f32x4 acc2c = {};
    #pragma unroll
    for (int ks2 = 0; ks2 < 8; ++ks2){
      int kb2 = ks2 * 64 + lq * 16;
      bf16x8 af2 = *(const bf16x8*)((const char*)Hc + lr * 512 + (kb2 ^ ((lr & 7) << 4)));
      acc2c = __builtin_amdgcn_mfma_f32_16x16x32_bf16(af2, w2fc[ks2], acc2c, 0, 0, 0);
    }
    int col = w * 16 + lr;
    float bv = b2[col];
    #pragma unroll
    for (int j = 0; j < 4; ++j){
      int rr = c0 + lq * 4 + j;
      redc[(size_t)rr * 64 + col] = acc2c[j] + bv;
    }
  }
}

// =================== k_mixgru: mix + GRU, 512 blocks x 32 rows ==============
__global__ __launch_bounds__(512, 4) void k_mixgru(
    const u16* __restrict__ qb, const u8* __restrict__ cb8,
    const float* __restrict__ qn, const float* __restrict__ cn,
    const int* __restrict__ rci, const int* __restrict__ filt,
    const float* __restrict__ redq, const float* __restrict__ redc,
    const float* __restrict__ h, const float* __restrict__ emb,
    const float* __restrict__ op, const float* __restrict__ Wp,
    const float* __restrict__ bp, const u16* __restrict__ WxhT,
    const float* __restrict__ bxh, float* __restrict__ prob_out,
    float* __restrict__ outh)
{
  __shared__ u16 XH[32 * 320];     // 20 KB, row stride 640 B, XOR-swizzled
  __shared__ u16 Bs[256 * 64];     // 32 KB
  const int tid = threadIdx.x;
  const int lane = tid & 63;
  const int w = tid >> 6;
  const int m0 = blockIdx.x << 5;

  auto stageB = [&](int kt){
    #pragma unroll
    for (int i = 0; i < 4; ++i){
      int cc = i * 512 + tid;
      int r2 = cc >> 3, s2 = cc & 7;
      gload16(WxhT + (size_t)r2 * 320 + kt * 64 + ((s2 ^ (r2 & 7)) << 3), &Bs[cc * 8]);
    }
  };
  stageB(0);   // flies under the mix phase

  // ---------------- mix phase: 4 rows per wave ----------------
  for (int i = 0; i < 4; ++i){
    const int r = w * 4 + i;
    const int b = m0 + r;
    const u16* qrow = qb + (size_t)b * TDIM_ + lane * 16;
    u16x8 qa = *(const u16x8*)qrow;
    u16x8 qc = *(const u16x8*)(qrow + 8);
    float qf[16];
    #pragma unroll
    for (int k = 0; k < 8; ++k){ qf[k] = b2f(qa[k]); qf[8 + k] = b2f(qc[k]); }
    int idxm[MAXC_];
    #pragma unroll
    for (int m = 0; m < MAXC_; ++m) idxm[m] = rci[b * MAXC_ + m];
    float dots[MAXC_];
    #pragma unroll
    for (int m = 0; m < MAXC_; ++m){
      uint4 cw = *(const uint4*)(cb8 + (size_t)idxm[m] * TDIM_ + lane * 16);
      float s = 0.f; f32x2 p;
      p = unpk_fp8<false>(cw.x); s += qf[0]*p[0]  + qf[1]*p[1];
      p = unpk_fp8<true >(cw.x); s += qf[2]*p[0]  + qf[3]*p[1];
      p = unpk_fp8<false>(cw.y); s += qf[4]*p[0]  + qf[5]*p[1];
      p = unpk_fp8<true >(cw.y); s += qf[6]*p[0]  + qf[7]*p[1];
      p = unpk_fp8<false>(cw.z); s += qf[8]*p[0]  + qf[9]*p[1];
      p = unpk_fp8<true >(cw.z); s += qf[10]*p[0] + qf[11]*p[1];
      p = unpk_fp8<false>(cw.w); s += qf[12]*p[0] + qf[13]*p[1];
      p = unpk_fp8<true >(cw.w); s += qf[14]*p[0] + qf[15]*p[1];
      dots[m] = s;
    }
    #pragma unroll
    for (int o = 32; o; o >>= 1){
      #pragma unroll
      for (int m = 0; m < MAXC_; ++m) dots[m] += __shfl_xor(dots[m], o);
    }
    const float qnb = qn[b];
    float sv[MAXC_]; float mx = -3.0e38f;
    #pragma unroll
    for (int m = 0; m < MAXC_; ++m){
      float dnm = fmaxf(qnb * cn[idxm[m]], 1e-8f);
      float s = (filt[b * MAXC_ + m] == 0) ? -1e9f : dots[m] * (1.f / 32.f) / dnm;
      sv[m] = s; mx = fmaxf(mx, s);
    }
    float se = 0.f;
    #pragma unroll
    for (int m = 0; m < MAXC_; ++m){ sv[m] = __expf(sv[m] - mx); se += sv[m]; }
    const float inv = 1.f / se;
    float rep = 0.f;
    #pragma unroll
    for (int m = 0; m < MAXC_; ++m) rep += sv[m] * redc[(size_t)idxm[m] * D_ + lane];
    rep *= inv;
    const float v0 = redq[(size_t)b * D_ + lane];
    const float hv = h[(size_t)b * D_ + lane];
    const float e0 = emb[(size_t)b * 128 + lane];
    const float e1 = emb[(size_t)b * 128 + 64 + lane];
    float p = hv * Wp[lane] + v0 * Wp[64 + lane] + rep * Wp[128 + lane]
            + e0 * Wp[192 + lane] + e1 * Wp[256 + lane];
    p = wsum(p);
    if (lane == 0) prob_out[b] = p + bp[0];
    const float o = op[b], om = 1.f - o;
    auto xst = [&](int col, float v){
      *(u16*)((char*)XH + r * 640 + ((col * 2) ^ ((r & 7) << 4))) = f2b(v);
    };
    xst(lane,        v0 * o  + e0 * om);
    xst(64 + lane,   rep * o + e1 * om);
    xst(128 + lane,  v0 * om + e0 * o);
    xst(192 + lane,  rep * om + e1 * o);
    xst(256 + lane,  hv);
  }
  __syncthreads();

  // ---------------- GRU GEMM: [32,320]@[320,256], wave tile 16x64 ----------
  const int lr = lane & 15, lq = lane >> 4;
  const int rh = w & 1, cc = w >> 1;
  f32x4 acc[4] = {};
  for (int kt = 0; kt < 5; ++kt){
    VMW(0);
    BAR();
    #pragma unroll
    for (int ks = 0; ks < 2; ++ks){
      const int kb = ks * 64 + lq * 16;
      int rra = rh * 16 + lr;
      bf16x8 af = *(const bf16x8*)((const char*)XH + rra * 640 +
                                   ((kt * 128 + kb) ^ ((rra & 7) << 4)));
      bf16x8 bfr[4];
      #pragma unroll
      for (int fc = 0; fc < 4; ++fc){
        int rr = cc * 64 + fc * 16 + lr;
        bfr[fc] = *(const bf16x8*)((const char*)Bs + rr * 128 + (kb ^ ((rr & 7) << 4)));
      }
      #pragma unroll
      for (int fc = 0; fc < 4; ++fc)
        acc[fc] = __builtin_amdgcn_mfma_f32_16x16x32_bf16(af, bfr[fc], acc[fc], 0, 0, 0);
    }
    BAR();
    if (kt < 4) stageB(kt + 1);
  }
  const int d = cc * 16 + lr;
  float bg[4];
  #pragma unroll
  for (int g = 0; g < 4; ++g) bg[g] = bxh[cc * 64 + g * 16 + lr];
  #pragma unroll
  for (int j = 0; j < 4; ++j){
    float rv = sigf(acc[0][j] + bg[0]);
    float zv = sigf(acc[1][j] + bg[1]);
    float nv = tanhf(acc[2][j] + bg[2] + rv * (acc[3][j] + bg[3]));
    int rr = m0 + rh * 16 + lq * 4 + j;
    float hv = h[(size_t)rr * 64 + d];
    outh[(size_t)rr * 64 + d] = (1.f - zv) * nv + zv * hv;
  }
}

extern "C" void kernel_launch(void* const* d_in, const int* in_sizes, int n_in,
                              void* d_out, int out_size, void* d_ws, size_t ws_size,
                              hipStream_t stream) {
  const int*   prob_ids = (const int*)  d_in[0];
  const int*   rci      = (const int*)  d_in[1];
  const int*   filt     = (const int*)  d_in[2];
  const float* h        = (const float*)d_in[3];
  const float* emb      = (const float*)d_in[4];
  const float* op       = (const float*)d_in[5];
  const float* ex       = (const float*)d_in[6];
  const float* con      = (const float*)d_in[7];
  const float* W1       = (const float*)d_in[8];
  const float* b1       = (const float*)d_in[9];
  const float* W2       = (const float*)d_in[10];
  const float* b2       = (const float*)d_in[11];
  const float* Wp       = (const float*)d_in[12];
  const float* bp       = (const float*)d_in[13];
  const float* Wx       = (const float*)d_in[14];
  const float* Wh       = (const float*)d_in[15];
  const float* bx       = (const float*)d_in[16];
  const float* bh       = (const float*)d_in[17];
  float* out = (float*)d_out;

  char* w = (char*)d_ws;
  size_t off = 0;
  auto alloc = [&](size_t bytes){ size_t o = off; off = (off + bytes + 255) & ~(size_t)255; return o; };
  u16*   qb   = (u16*)  (w + alloc((size_t)B_ * TDIM_ * 2));      // 32 MB
  u16*   cb   = (u16*)  (w + alloc((size_t)NCONP_ * TDIM_ * 2));  // 4 MB
  u8*    cb8  = (u8*)   (w + alloc((size_t)NCONP_ * TDIM_));      // 2 MB
  float* qn   = (float*)(w + alloc((size_t)B_ * 4));
  float* cn   = (float*)(w + alloc((size_t)NCONP_ * 4));
  float* redq = (float*)(w + alloc((size_t)B_ * D_ * 4));         // 4 MB
  float* redc = (float*)(w + alloc((size_t)NCONP_ * D_ * 4));
  u16*   W1T  = (u16*)  (w + alloc((size_t)HID_ * TDIM_ * 2));
  u16*   W2T  = (u16*)  (w + alloc((size_t)D_ * HID_ * 2));
  u16*   WxhT = (u16*)  (w + alloc((size_t)256 * 320 * 2));
  float* bxh  = (float*)(w + alloc((size_t)256 * 4));

  k_prep<<<6017, 256, 0, stream>>>(ex, prob_ids, con, W1, W2, Wx, Wh, bx, bh,
                                   qb, qn, cb, cb8, cn, W1T, W2T, WxhT, bxh);
  k_mlp<<<256, 512, 0, stream>>>(qb, cb, W1T, b1, W2T, b2, redq, redc);
  k_mixgru<<<512, 512, 0, stream>>>(qb, cb8, qn, cn, rci, filt, redq, redc,
                                    h, emb, op, Wp, bp, WxhT, bxh, out, out + B_);
}

// Round 8
// 91.657 us; speedup vs baseline: 2.8154x; 1.4142x over previous
//
#include <hip/hip_runtime.h>
#include <cstdint>
#include <cstddef>

typedef unsigned short u16;
typedef unsigned char u8;
typedef __bf16 bf16x8 __attribute__((ext_vector_type(8)));
typedef float f32x4 __attribute__((ext_vector_type(4)));
typedef float f32x2 __attribute__((ext_vector_type(2)));
typedef u16 u16x4 __attribute__((ext_vector_type(4)));
typedef u16 u16x8 __attribute__((ext_vector_type(8)));

#define B_ 16384
#define D_ 64
#define MAXC_ 8
#define NCON_ 2000
#define NCONP_ 2048
#define TDIM_ 1024
#define HID_ 256

#define VMW(n) asm volatile("s_waitcnt vmcnt(" #n ")" ::: "memory")
#define BAR() __builtin_amdgcn_s_barrier()

__device__ inline u16 f2b(float f){
  unsigned u = __float_as_uint(f);
  u += 0x7fffu + ((u >> 16) & 1u);
  return (u16)(u >> 16);
}
__device__ inline float b2f(u16 u){ return __uint_as_float(((unsigned)u) << 16); }

__device__ inline unsigned pk2fp8(float a, float b){
  return (unsigned)__builtin_amdgcn_cvt_pk_fp8_f32(a, b, 0, false);
}
template<bool HI>
__device__ inline f32x2 unpk_fp8(unsigned v){
  return __builtin_amdgcn_cvt_pk_f32_fp8(v, HI);
}

__device__ inline void gload16(const void* g, void* l){
  __builtin_amdgcn_global_load_lds((const __attribute__((address_space(1))) unsigned*)g,
                                   (__attribute__((address_space(3))) unsigned*)l, 16, 0, 0);
}

__device__ inline float wsum(float v){
  #pragma unroll
  for (int o = 32; o; o >>= 1) v += __shfl_xor(v, o);
  return v;
}
__device__ inline float sigf(float x){ return 1.f / (1.f + __expf(-x)); }

// =================== k_prep ================================================
// [0,4096): q gather -> qb(bf16)+qn ; [4096,4608): concepts -> cb,cb8,cn ;
// [4608,6017): weights
__global__ __launch_bounds__(256) void k_prep(
    const float* __restrict__ ex, const int* __restrict__ pid,
    const float* __restrict__ con,
    const float* __restrict__ W1, const float* __restrict__ W2,
    const float* __restrict__ Wx, const float* __restrict__ Wh,
    const float* __restrict__ bx, const float* __restrict__ bh,
    u16* __restrict__ qb, float* __restrict__ qn,
    u16* __restrict__ cb, u8* __restrict__ cb8, float* __restrict__ cn,
    u16* __restrict__ W1T, u16* __restrict__ W2T, u16* __restrict__ WxhT,
    float* __restrict__ bxh)
{
  const int bid = blockIdx.x, tid = threadIdx.x;
  const int lane = tid & 63;
  if (bid < 4096){                                  // ---- q gather ----
    const int b = bid * 4 + (tid >> 6);
    const float* src = ex + (size_t)pid[b] * TDIM_;
    u16* dst = qb + (size_t)b * TDIM_;
    float ss = 0.f;
    #pragma unroll
    for (int c = 0; c < 4; ++c){
      float4 v = *(const float4*)(src + c * 256 + lane * 4);
      ss += v.x*v.x + v.y*v.y + v.z*v.z + v.w*v.w;
      u16x4 o = { f2b(v.x), f2b(v.y), f2b(v.z), f2b(v.w) };
      *(u16x4*)(dst + c * 256 + lane * 4) = o;
    }
    ss = wsum(ss);
    if (lane == 0) qn[b] = sqrtf(ss);
  } else if (bid < 4608){                           // ---- concepts ----
    const int r = (bid - 4096) * 4 + (tid >> 6);
    u16* dst = cb + (size_t)r * TDIM_;
    u8*  dst8 = cb8 + (size_t)r * TDIM_;
    if (r < NCON_){
      const float* src = con + (size_t)r * TDIM_;
      float ss = 0.f;
      #pragma unroll
      for (int c = 0; c < 4; ++c){
        float4 v = *(const float4*)(src + c * 256 + lane * 4);
        ss += v.x*v.x + v.y*v.y + v.z*v.z + v.w*v.w;
        u16x4 o = { f2b(v.x), f2b(v.y), f2b(v.z), f2b(v.w) };
        *(u16x4*)(dst + c * 256 + lane * 4) = o;
        unsigned lo = pk2fp8(v.x * 32.f, v.y * 32.f);
        unsigned hi = pk2fp8(v.z * 32.f, v.w * 32.f);
        *(unsigned*)(dst8 + c * 256 + lane * 4) = (lo & 0xffffu) | (hi << 16);
      }
      ss = wsum(ss);
      if (lane == 0) cn[r] = sqrtf(ss);
    } else {
      u16x4 z = { 0, 0, 0, 0 };
      #pragma unroll
      for (int c = 0; c < 4; ++c){
        *(u16x4*)(dst + c * 256 + lane * 4) = z;
        *(unsigned*)(dst8 + c * 256 + lane * 4) = 0u;
      }
    }
  } else {                                          // ---- weights ----
    int gid = (bid - 4608) * 256 + tid;
    if (gid < 262144){                       // W1T: n*1024 + k
      int n = gid >> 10, k = gid & 1023;
      W1T[gid] = f2b(W1[(size_t)k * 256 + n]);
    } else if (gid < 278528){                // W2T: n*256 + k
      int t = gid - 262144;
      int n = t >> 8, k = t & 255;
      W2T[t] = f2b(W2[(size_t)k * 64 + n]);
    } else if (gid < 360448){                // WxhT: c*320 + k, gate-interleaved
      int t = gid - 278528;
      int c = t / 320, k = t % 320;
      int g = (c >> 4) & 3;
      int d = (c >> 6) * 16 + (c & 15);
      float v = 0.f;
      if (k < 256){
        if (g == 0)      v = Wx[(size_t)k * 192 + d];
        else if (g == 1) v = Wx[(size_t)k * 192 + 64 + d];
        else if (g == 2) v = Wx[(size_t)k * 192 + 128 + d];
      } else {
        int kh = k - 256;
        if (g == 0)      v = Wh[(size_t)kh * 192 + d];
        else if (g == 1) v = Wh[(size_t)kh * 192 + 64 + d];
        else if (g == 3) v = Wh[(size_t)kh * 192 + 128 + d];
      }
      WxhT[t] = f2b(v);
    } else if (gid < 360704){                // bxh
      int c = gid - 360448;
      int g = (c >> 4) & 3;
      int d = (c >> 6) * 16 + (c & 15);
      float v;
      if (g == 0)      v = bx[d] + bh[d];
      else if (g == 1) v = bx[64 + d] + bh[64 + d];
      else if (g == 2) v = bx[128 + d];
      else             v = bh[128 + d];
      bxh[c] = v;
    }
  }
}

// =================== k_mlp: red = relu(A@W1+b1)@W2+b2 =======================
// BM=32, 576 blocks x 512 thr (blocks [0,512): q rows; [512,576): c rows).
// LDS 52 KB -> 2 blocks/CU co-resident. No VGPR cap; no register hoards.
__global__ __launch_bounds__(512) void k_mlp(
    const u16* __restrict__ qb, const u16* __restrict__ cb,
    const u16* __restrict__ W1T, const float* __restrict__ b1,
    const u16* __restrict__ W2T, const float* __restrict__ b2,
    float* __restrict__ redq, float* __restrict__ redc)
{
  __shared__ u16 As[32 * 64];      // 4 KB
  __shared__ u16 Bs[256 * 64];     // 32 KB
  __shared__ u16 Hs[32 * 256];     // 16 KB
  const int tid = threadIdx.x;
  const int lane = tid & 63;
  const int w = tid >> 6;
  const int lr = lane & 15, lq = lane >> 4;
  const bool qside = blockIdx.x < 512;
  const u16* Abase = qside ? qb : cb;
  float* Obase = qside ? redq : redc;
  const int m0 = (qside ? (int)blockIdx.x : ((int)blockIdx.x - 512)) << 5;
  const int rf = w & 1, ch = w >> 1;
  const int arow = tid >> 3, asub = tid & 7;

  f32x4 acc[4] = {};
  for (int kt = 0; kt < 16; ++kt){
    if (tid < 256)
      gload16(Abase + (size_t)(m0 + arow) * 1024 + kt * 64 + ((asub ^ (arow & 7)) << 3),
              &As[tid * 8]);
    #pragma unroll
    for (int i = 0; i < 4; ++i){
      int cc = i * 512 + tid;
      int r2 = cc >> 3, s2 = cc & 7;
      gload16(W1T + (size_t)r2 * 1024 + kt * 64 + ((s2 ^ (r2 & 7)) << 3), &Bs[cc * 8]);
    }
    VMW(0);
    BAR();
    #pragma unroll
    for (int ks = 0; ks < 2; ++ks){
      const int kb = ks * 64 + lq * 16;
      const int ra = rf * 16 + lr;
      bf16x8 af = *(const bf16x8*)((const char*)As + ra * 128 + (kb ^ ((ra & 7) << 4)));
      #pragma unroll
      for (int fc = 0; fc < 4; ++fc){
        int rb = ch * 64 + fc * 16 + lr;
        bf16x8 bf = *(const bf16x8*)((const char*)Bs + rb * 128 + (kb ^ ((rb & 7) << 4)));
        acc[fc] = __builtin_amdgcn_mfma_f32_16x16x32_bf16(af, bf, acc[fc], 0, 0, 0);
      }
    }
    BAR();
  }
  // hidden -> LDS (bias + relu + bf16), swizzled
  #pragma unroll
  for (int fc = 0; fc < 4; ++fc){
    int col = ch * 64 + fc * 16 + lr;
    float bv = b1[col];
    #pragma unroll
    for (int j = 0; j < 4; ++j){
      int rr = rf * 16 + lq * 4 + j;
      float v = fmaxf(acc[fc][j] + bv, 0.f);
      *(u16*)((char*)Hs + rr * 512 + ((col * 2) ^ ((rr & 7) << 4))) = f2b(v);
    }
  }
  __syncthreads();
  // layer 2: [32,256] @ W2T[64,256]^T -> [32,64]; wave (rf2,cp) owns 16x16
  const int rf2 = w & 1, cp = w >> 1;
  f32x4 acc2 = {};
  #pragma unroll
  for (int ks2 = 0; ks2 < 8; ++ks2){
    int rr = rf2 * 16 + lr;
    int kb2 = ks2 * 64 + lq * 16;
    bf16x8 af2 = *(const bf16x8*)((const char*)Hs + rr * 512 + (kb2 ^ ((rr & 7) << 4)));
    bf16x8 w2 = *(const bf16x8*)(W2T + (size_t)(cp * 16 + lr) * 256 + ks2 * 32 + lq * 8);
    acc2 = __builtin_amdgcn_mfma_f32_16x16x32_bf16(af2, w2, acc2, 0, 0, 0);
  }
  {
    int col = cp * 16 + lr;
    float bv = b2[col];
    #pragma unroll
    for (int j = 0; j < 4; ++j){
      int rr = m0 + rf2 * 16 + lq * 4 + j;
      Obase[(size_t)rr * 64 + col] = acc2[j] + bv;
    }
  }
}

// =================== k_mixgru: mix + GRU, 512 blocks x 32 rows ==============
__global__ __launch_bounds__(512, 4) void k_mixgru(
    const u16* __restrict__ qb, const u8* __restrict__ cb8,
    const float* __restrict__ qn, const float* __restrict__ cn,
    const int* __restrict__ rci, const int* __restrict__ filt,
    const float* __restrict__ redq, const float* __restrict__ redc,
    const float* __restrict__ h, const float* __restrict__ emb,
    const float* __restrict__ op, const float* __restrict__ Wp,
    const float* __restrict__ bp, const u16* __restrict__ WxhT,
    const float* __restrict__ bxh, float* __restrict__ prob_out,
    float* __restrict__ outh)
{
  __shared__ u16 XH[32 * 320];     // 20 KB, row stride 640 B, XOR-swizzled
  __shared__ u16 Bs[256 * 64];     // 32 KB
  const int tid = threadIdx.x;
  const int lane = tid & 63;
  const int w = tid >> 6;
  const int m0 = blockIdx.x << 5;

  auto stageB = [&](int kt){
    #pragma unroll
    for (int i = 0; i < 4; ++i){
      int cc = i * 512 + tid;
      int r2 = cc >> 3, s2 = cc & 7;
      gload16(WxhT + (size_t)r2 * 320 + kt * 64 + ((s2 ^ (r2 & 7)) << 3), &Bs[cc * 8]);
    }
  };
  stageB(0);   // flies under the mix phase

  // ---------------- mix phase: 4 rows per wave ----------------
  for (int i = 0; i < 4; ++i){
    const int r = w * 4 + i;
    const int b = m0 + r;
    const u16* qrow = qb + (size_t)b * TDIM_ + lane * 16;
    u16x8 qa = *(const u16x8*)qrow;
    u16x8 qc = *(const u16x8*)(qrow + 8);
    float qf[16];
    #pragma unroll
    for (int k = 0; k < 8; ++k){ qf[k] = b2f(qa[k]); qf[8 + k] = b2f(qc[k]); }
    int idxm[MAXC_];
    #pragma unroll
    for (int m = 0; m < MAXC_; ++m) idxm[m] = rci[b * MAXC_ + m];
    float dots[MAXC_];
    #pragma unroll
    for (int m = 0; m < MAXC_; ++m){
      uint4 cw = *(const uint4*)(cb8 + (size_t)idxm[m] * TDIM_ + lane * 16);
      float s = 0.f; f32x2 p;
      p = unpk_fp8<false>(cw.x); s += qf[0]*p[0]  + qf[1]*p[1];
      p = unpk_fp8<true >(cw.x); s += qf[2]*p[0]  + qf[3]*p[1];
      p = unpk_fp8<false>(cw.y); s += qf[4]*p[0]  + qf[5]*p[1];
      p = unpk_fp8<true >(cw.y); s += qf[6]*p[0]  + qf[7]*p[1];
      p = unpk_fp8<false>(cw.z); s += qf[8]*p[0]  + qf[9]*p[1];
      p = unpk_fp8<true >(cw.z); s += qf[10]*p[0] + qf[11]*p[1];
      p = unpk_fp8<false>(cw.w); s += qf[12]*p[0] + qf[13]*p[1];
      p = unpk_fp8<true >(cw.w); s += qf[14]*p[0] + qf[15]*p[1];
      dots[m] = s;
    }
    #pragma unroll
    for (int o = 32; o; o >>= 1){
      #pragma unroll
      for (int m = 0; m < MAXC_; ++m) dots[m] += __shfl_xor(dots[m], o);
    }
    const float qnb = qn[b];
    float sv[MAXC_]; float mx = -3.0e38f;
    #pragma unroll
    for (int m = 0; m < MAXC_; ++m){
      float dnm = fmaxf(qnb * cn[idxm[m]], 1e-8f);
      float s = (filt[b * MAXC_ + m] == 0) ? -1e9f : dots[m] * (1.f / 32.f) / dnm;
      sv[m] = s; mx = fmaxf(mx, s);
    }
    float se = 0.f;
    #pragma unroll
    for (int m = 0; m < MAXC_; ++m){ sv[m] = __expf(sv[m] - mx); se += sv[m]; }
    const float inv = 1.f / se;
    float rep = 0.f;
    #pragma unroll
    for (int m = 0; m < MAXC_; ++m) rep += sv[m] * redc[(size_t)idxm[m] * D_ + lane];
    rep *= inv;
    const float v0 = redq[(size_t)b * D_ + lane];
    const float hv = h[(size_t)b * D_ + lane];
    const float e0 = emb[(size_t)b * 128 + lane];
    const float e1 = emb[(size_t)b * 128 + 64 + lane];
    float p = hv * Wp[lane] + v0 * Wp[64 + lane] + rep * Wp[128 + lane]
            + e0 * Wp[192 + lane] + e1 * Wp[256 + lane];
    p = wsum(p);
    if (lane == 0) prob_out[b] = p + bp[0];
    const float o = op[b], om = 1.f - o;
    auto xst = [&](int col, float v){
      *(u16*)((char*)XH + r * 640 + ((col * 2) ^ ((r & 7) << 4))) = f2b(v);
    };
    xst(lane,        v0 * o  + e0 * om);
    xst(64 + lane,   rep * o + e1 * om);
    xst(128 + lane,  v0 * om + e0 * o);
    xst(192 + lane,  rep * om + e1 * o);
    xst(256 + lane,  hv);
  }
  __syncthreads();

  // ---------------- GRU GEMM: [32,320]@[320,256], wave tile 16x64 ----------
  const int lr = lane & 15, lq = lane >> 4;
  const int rh = w & 1, cc = w >> 1;
  f32x4 acc[4] = {};
  for (int kt = 0; kt < 5; ++kt){
    VMW(0);
    BAR();
    #pragma unroll
    for (int ks = 0; ks < 2; ++ks){
      const int kb = ks * 64 + lq * 16;
      int rra = rh * 16 + lr;
      bf16x8 af = *(const bf16x8*)((const char*)XH + rra * 640 +
                                   ((kt * 128 + kb) ^ ((rra & 7) << 4)));
      bf16x8 bfr[4];
      #pragma unroll
      for (int fc = 0; fc < 4; ++fc){
        int rr = cc * 64 + fc * 16 + lr;
        bfr[fc] = *(const bf16x8*)((const char*)Bs + rr * 128 + (kb ^ ((rr & 7) << 4)));
      }
      #pragma unroll
      for (int fc = 0; fc < 4; ++fc)
        acc[fc] = __builtin_amdgcn_mfma_f32_16x16x32_bf16(af, bfr[fc], acc[fc], 0, 0, 0);
    }
    BAR();
    if (kt < 4) stageB(kt + 1);
  }
  const int d = cc * 16 + lr;
  float bg[4];
  #pragma unroll
  for (int g = 0; g < 4; ++g) bg[g] = bxh[cc * 64 + g * 16 + lr];
  #pragma unroll
  for (int j = 0; j < 4; ++j){
    float rv = sigf(acc[0][j] + bg[0]);
    float zv = sigf(acc[1][j] + bg[1]);
    float nv = tanhf(acc[2][j] + bg[2] + rv * (acc[3][j] + bg[3]));
    int rr = m0 + rh * 16 + lq * 4 + j;
    float hv = h[(size_t)rr * 64 + d];
    outh[(size_t)rr * 64 + d] = (1.f - zv) * nv + zv * hv;
  }
}

extern "C" void kernel_launch(void* const* d_in, const int* in_sizes, int n_in,
                              void* d_out, int out_size, void* d_ws, size_t ws_size,
                              hipStream_t stream) {
  const int*   prob_ids = (const int*)  d_in[0];
  const int*   rci      = (const int*)  d_in[1];
  const int*   filt     = (const int*)  d_in[2];
  const float* h        = (const float*)d_in[3];
  const float* emb      = (const float*)d_in[4];
  const float* op       = (const float*)d_in[5];
  const float* ex       = (const float*)d_in[6];
  const float* con      = (const float*)d_in[7];
  const float* W1       = (const float*)d_in[8];
  const float* b1       = (const float*)d_in[9];
  const float* W2       = (const float*)d_in[10];
  const float* b2       = (const float*)d_in[11];
  const float* Wp       = (const float*)d_in[12];
  const float* bp       = (const float*)d_in[13];
  const float* Wx       = (const float*)d_in[14];
  const float* Wh       = (const float*)d_in[15];
  const float* bx       = (const float*)d_in[16];
  const float* bh       = (const float*)d_in[17];
  float* out = (float*)d_out;

  char* w = (char*)d_ws;
  size_t off = 0;
  auto alloc = [&](size_t bytes){ size_t o = off; off = (off + bytes + 255) & ~(size_t)255; return o; };
  u16*   qb   = (u16*)  (w + alloc((size_t)B_ * TDIM_ * 2));      // 32 MB
  u16*   cb   = (u16*)  (w + alloc((size_t)NCONP_ * TDIM_ * 2));  // 4 MB
  u8*    cb8  = (u8*)   (w + alloc((size_t)NCONP_ * TDIM_));      // 2 MB
  float* qn   = (float*)(w + alloc((size_t)B_ * 4));
  float* cn   = (float*)(w + alloc((size_t)NCONP_ * 4));
  float* redq = (float*)(w + alloc((size_t)B_ * D_ * 4));         // 4 MB
  float* redc = (float*)(w + alloc((size_t)NCONP_ * D_ * 4));
  u16*   W1T  = (u16*)  (w + alloc((size_t)HID_ * TDIM_ * 2));
  u16*   W2T  = (u16*)  (w + alloc((size_t)D_ * HID_ * 2));
  u16*   WxhT = (u16*)  (w + alloc((size_t)256 * 320 * 2));
  float* bxh  = (float*)(w + alloc((size_t)256 * 4));

  k_prep<<<6017, 256, 0, stream>>>(ex, prob_ids, con, W1, W2, Wx, Wh, bx, bh,
                                   qb, qn, cb, cb8, cn, W1T, W2T, WxhT, bxh);
  k_mlp<<<576, 512, 0, stream>>>(qb, cb, W1T, b1, W2T, b2, redq, redc);
  k_mixgru<<<512, 512, 0, stream>>>(qb, cb8, qn, cn, rci, filt, redq, redc,
                                    h, emb, op, Wp, bp, WxhT, bxh, out, out + B_);
}